// Round 7
// baseline (216.030 us; speedup 1.0000x reference)
//
#include <hip/hip_runtime.h>
#include <hip/hip_bf16.h>
#include <cstdint>
#include <cstddef>

// Problem constants
#define B_   2
#define T_   4096
#define E_   1024
#define H_   16
#define D_   64
#define M_   (B_ * T_)       // 8192 rows
#define KDIM 1024
#define NDIM 1024
#define EPSC 1e-6f
#define CT   128             // chunk length
#define NC   (T_ / CT)       // 32 chunks per (b,h)

typedef __attribute__((ext_vector_type(8))) short bf16x8;
typedef __attribute__((ext_vector_type(4))) float f32x4;

// ---------- small helpers ----------
__device__ __forceinline__ float bf2f(uint32_t u) {
    union { uint32_t u; float f; } x; x.u = u << 16; return x.f;
}
__device__ __forceinline__ unsigned short f2bf(float f) {
    union { float f; uint32_t u; } x; x.f = f;
    uint32_t r = x.u + 0x7fffu + ((x.u >> 16) & 1u);   // RNE
    return (unsigned short)(r >> 16);
}
__device__ __forceinline__ void gload16(const void* g, void* l) {
    __builtin_amdgcn_global_load_lds(
        (const __attribute__((address_space(1))) void*)g,
        (__attribute__((address_space(3))) void*)l, 16, 0, 0);
}

// ---------------------------------------------------------------------------
// fp32 -> bf16 bulk convert (x). Each thread: 8 floats.
// ---------------------------------------------------------------------------
__global__ __launch_bounds__(256) void conv_bf16(
    const float* __restrict__ in, unsigned short* __restrict__ out)
{
    const int i = blockIdx.x * 256 + threadIdx.x;
    const float4* p = (const float4*)in;
    float4 a = p[i * 2], b = p[i * 2 + 1];
    ushort4 o0 = make_ushort4(f2bf(a.x), f2bf(a.y), f2bf(a.z), f2bf(a.w));
    ushort4 o1 = make_ushort4(f2bf(b.x), f2bf(b.y), f2bf(b.z), f2bf(b.w));
    *(ushort4*)&out[(size_t)i * 8] = o0;
    *(ushort4*)&out[(size_t)i * 8 + 4] = o1;
}

// ---------------------------------------------------------------------------
// Transpose + convert the four 1024x1024 fp32 weights to bf16 [N][K].
// o0..o2 written contiguously (one [3072][1024] matrix for fused QKV).
// ---------------------------------------------------------------------------
__global__ __launch_bounds__(256) void transpose_w4(
    const float* __restrict__ w0, const float* __restrict__ w1,
    const float* __restrict__ w2, const float* __restrict__ w3,
    unsigned short* __restrict__ o0, unsigned short* __restrict__ o1,
    unsigned short* __restrict__ o2, unsigned short* __restrict__ o3)
{
    const float* src; unsigned short* dst;
    switch (blockIdx.z) {
        case 0: src = w0; dst = o0; break;
        case 1: src = w1; dst = o1; break;
        case 2: src = w2; dst = o2; break;
        default: src = w3; dst = o3; break;
    }
    __shared__ float tile[64][65];
    const int t = threadIdx.x, tx = t & 63, ty = t >> 6;
    const int r0 = blockIdx.y * 64, c0 = blockIdx.x * 64;
#pragma unroll
    for (int i = 0; i < 16; ++i)
        tile[ty + i * 4][tx] = src[(size_t)(r0 + ty + i * 4) * KDIM + c0 + tx];
    __syncthreads();
#pragma unroll
    for (int i = 0; i < 16; ++i)
        dst[(size_t)(c0 + ty + i * 4) * KDIM + r0 + tx] = f2bf(tile[tx][ty + i * 4]);
}

// ---------------------------------------------------------------------------
// Fused QKV GEMM, m97-mechanism at scale (co-residency hides drains):
//   BM=256, BN=128, BK=64, 4 waves (2x2, per-wave 128x64 output).
//   48 KB single-buffer LDS -> 3 blocks/CU; grid 768 = 3 x 256 -> ALL blocks
//   co-resident, zero tail. Per tile: {12x gload16 -> sync -> 24x ds_read +
//   64 MFMA -> sync} (m97 pattern; cross-block overlap hides vmcnt drain).
//   XOR swizzle ((row&7)<<4) via pre-swizzled global sources (0 conflicts).
//   Epilogue: 2-pass LDS staging (128-row halves) -> coalesced 16B stores.
// ---------------------------------------------------------------------------
__global__ __launch_bounds__(256) void gemm_qkv_x(
    const unsigned short* __restrict__ A,    // [8192][1024] bf16
    const unsigned short* __restrict__ Wt,   // [3072][1024] bf16 (N-major)
    const float* __restrict__ bq, const float* __restrict__ bk,
    const float* __restrict__ bv,
    unsigned short* __restrict__ qb,  unsigned short* __restrict__ kb,
    unsigned short* __restrict__ ktb, unsigned short* __restrict__ vtb)
{
    __shared__ char lds[49152];   // A: 32KB @0 (256 rows x 128B), B: 16KB @32K

    const int tid  = threadIdx.x;
    const int lane = tid & 63;
    const int w    = tid >> 6;       // 0..3
    const int wm   = w >> 1;         // 0..1 (row half, 128 rows)
    const int wn   = w & 1;          // 0..1 (col half, 64 cols)
    const int lo   = lane & 15, hi = lane >> 4;

    // XCD-chunked bijective swizzle: 768 blocks, 768 % 8 == 0
    const int orig = blockIdx.x;
    const int swz  = (orig & 7) * 96 + (orig >> 3);
    const int bx = swz % 24;         // 24 col tiles of 128 (0-7 Q, 8-15 K, 16-23 V)
    const int by = swz / 24;         // 32 row tiles of 256
    const int row0 = by * 256;
    const int col0 = bx * 128;

    // Pre-swizzled staging sources: chunk ch covers dest bytes
    // [ch*4096, ch*4096+4096); thread's dest byte X = ch*4096 + tid*16
    // (linear, as global_load_lds requires); logical Y = X ^ (((X>>7)&7)<<4);
    // row = Y>>7, k-elem = (Y&127)>>1.
    const unsigned short* pA[8];
    const unsigned short* pB[4];
#pragma unroll
    for (int ch = 0; ch < 8; ++ch) {
        int X = ch * 4096 + tid * 16;
        int Y = X ^ (((X >> 7) & 7) << 4);
        pA[ch] = A + (size_t)(row0 + (Y >> 7)) * KDIM + ((Y & 127) >> 1);
    }
#pragma unroll
    for (int ch = 0; ch < 4; ++ch) {
        int X = ch * 4096 + tid * 16;
        int Y = X ^ (((X >> 7) & 7) << 4);
        pB[ch] = Wt + (size_t)(col0 + (Y >> 7)) * KDIM + ((Y & 127) >> 1);
    }

    // ds_read frag offsets: logical col-byte (kk*64 + hi*16) XOR ((row&7)<<4);
    // row&7 == lo&7 for all fragment rows (row bases are multiples of 16).
    const int koff0 = (hi * 16)      ^ ((lo & 7) << 4);
    const int koff1 = (64 + hi * 16) ^ ((lo & 7) << 4);

    const char* ldsA = lds;
    const char* ldsB = lds + 32768;

    f32x4 acc[8][4] = {};

    for (int t = 0; t < KDIM / 64; ++t) {
        // stage tile t (single buffer; sync provides the full drain; the
        // exposed latency is hidden by the 2 other co-resident blocks)
#pragma unroll
        for (int ch = 0; ch < 8; ++ch)
            gload16(pA[ch] + t * 64, lds + ch * 4096 + tid * 16);
#pragma unroll
        for (int ch = 0; ch < 4; ++ch)
            gload16(pB[ch] + t * 64, lds + 32768 + ch * 4096 + tid * 16);
        __syncthreads();

#pragma unroll
        for (int kk = 0; kk < 2; ++kk) {
            const int ko = kk ? koff1 : koff0;
            bf16x8 af[8], bfr[4];
#pragma unroll
            for (int m = 0; m < 8; ++m)
                af[m] = *(const bf16x8*)(ldsA + (wm * 128 + m * 16 + lo) * 128 + ko);
#pragma unroll
            for (int n = 0; n < 4; ++n)
                bfr[n] = *(const bf16x8*)(ldsB + (wn * 64 + n * 16 + lo) * 128 + ko);
#pragma unroll
            for (int m = 0; m < 8; ++m)
#pragma unroll
                for (int n = 0; n < 4; ++n)
                    acc[m][n] = __builtin_amdgcn_mfma_f32_16x16x32_bf16(
                        af[m], bfr[n], acc[m][n], 0, 0, 0);
        }
        __syncthreads();   // all reads done before next-tile restage
    }

    // ---- epilogue: 2 passes (wm halves) through [128][136] LDS tile ----
    // C/D mapping: col=lane&15, row=(lane>>4)*4+j  [m89/m91 verified]
    unsigned short* ep = (unsigned short*)lds;   // 34.8 KB <= 48 KB
    const int matid = bx >> 3;                   // 0=Q 1=K 2=V
    const float* bias = (matid == 0) ? bq : (matid == 1) ? bk : bv;
    const int b   = row0 >> 12;
    const int tg0 = row0 & (T_ - 1);
    const int h0  = (bx & 7) * 2;

#pragma unroll
    for (int pass = 0; pass < 2; ++pass) {
        if (wm == pass) {
#pragma unroll
            for (int n = 0; n < 4; ++n) {
                const int col = wn * 64 + n * 16 + lo;
                const float bval = bias[(bx & 7) * 128 + col];
#pragma unroll
                for (int m = 0; m < 8; ++m) {
#pragma unroll
                    for (int j = 0; j < 4; ++j) {
                        float v = acc[m][n][j] + bval;
                        if (matid <= 1) v = (v > 0.f) ? (v + 1.f) : __expf(v);
                        ep[(m * 16 + hi * 4 + j) * 136 + col] = f2bf(v);
                    }
                }
            }
        }
        __syncthreads();

        if (matid <= 1) {                // row-major out: qb or kb [B,H,T,D]
            unsigned short* dst0 = (matid == 0) ? qb : kb;
#pragma unroll
            for (int it = 0; it < 8; ++it) {
                const int vid = it * 256 + tid;     // 0..2047
                const int head = vid >> 10;
                const int rem = vid & 1023;
                const int tr = rem >> 3, c8 = rem & 7;
                uint4 v = *(const uint4*)&ep[tr * 136 + head * 64 + c8 * 8];
                *(uint4*)&dst0[((size_t)((b * H_ + h0 + head) * T_)
                                + tg0 + pass * 128 + tr) * D_ + c8 * 8] = v;
            }
        }
        if (matid >= 1) {                // transposed out: ktb or vtb [B,H,D,T]
            unsigned short* dstT = (matid == 1) ? ktb : vtb;
#pragma unroll
            for (int it = 0; it < 8; ++it) {
                const int vid = it * 256 + tid;
                const int head = vid >> 10;
                const int rem = vid & 1023;
                const int d = rem & 63, t8 = rem >> 6;   // d fast: conflict-free
                unsigned short vals[8];
#pragma unroll
                for (int i = 0; i < 8; ++i)
                    vals[i] = ep[(t8 * 8 + i) * 136 + head * 64 + d];
                *(uint4*)&dstT[((size_t)((b * H_ + h0 + head) * D_) + d) * T_
                               + tg0 + pass * 128 + t8 * 8] = *(const uint4*)vals;
            }
        }
        __syncthreads();   // before next pass overwrites ep
    }
}

// ---------------------------------------------------------------------------
// Output projection GEMM (m97 structure, proven) + XCD swizzle. f32 out.
// ---------------------------------------------------------------------------
__global__ __launch_bounds__(256) void gemm_out(
    const unsigned short* __restrict__ A,   // attb [8192][1024] bf16
    const unsigned short* __restrict__ Bt,  // woT [1024][1024] bf16
    const float* __restrict__ bias, float* __restrict__ outf)
{
    __shared__ unsigned short As[128 * 32];
    __shared__ unsigned short Bs[128 * 32];

    const int tid  = threadIdx.x;
    const int lane = tid & 63;
    const int wave = tid >> 6;
    const int wr = wave >> 1, wc = wave & 1;
    const int orig = blockIdx.x;                 // 512 blocks
    const int swz  = (orig & 7) * 64 + (orig >> 3);
    const int bx = swz & 7, by = swz >> 3;
    const int row0 = by * 128;
    const int col0 = bx * 128;

    f32x4 acc[4][4] = {};

    const unsigned short* Ag = A  + (size_t)(row0 + (tid >> 2)) * KDIM + (tid & 3) * 8;
    const unsigned short* Bg = Bt + (size_t)(col0 + (tid >> 2)) * KDIM + (tid & 3) * 8;
    unsigned short* AsW = As + wave * 512;
    unsigned short* BsW = Bs + wave * 512;

    const int fr = lane & 15;
    const int fk = (lane >> 4) * 8;

    for (int k0 = 0; k0 < KDIM; k0 += 32) {
        gload16(Ag + k0,              AsW);
        gload16(Ag + 64 * KDIM + k0,  AsW + 2048);
        gload16(Bg + k0,              BsW);
        gload16(Bg + 64 * KDIM + k0,  BsW + 2048);
        __syncthreads();

        bf16x8 af[4], bfr[4];
#pragma unroll
        for (int m = 0; m < 4; ++m)
            af[m] = *(const bf16x8*)&As[(wr * 64 + m * 16 + fr) * 32 + fk];
#pragma unroll
        for (int n = 0; n < 4; ++n)
            bfr[n] = *(const bf16x8*)&Bs[(wc * 64 + n * 16 + fr) * 32 + fk];
#pragma unroll
        for (int m = 0; m < 4; ++m)
#pragma unroll
            for (int n = 0; n < 4; ++n)
                acc[m][n] = __builtin_amdgcn_mfma_f32_16x16x32_bf16(
                    af[m], bfr[n], acc[m][n], 0, 0, 0);
        __syncthreads();
    }

    const int fcol = lane & 15;
    const int frow = (lane >> 4) * 4;
#pragma unroll
    for (int m = 0; m < 4; ++m) {
#pragma unroll
        for (int n = 0; n < 4; ++n) {
            const int col = col0 + wc * 64 + n * 16 + fcol;
            const float bval = bias[col];
            const int rbase = row0 + wr * 64 + m * 16 + frow;
#pragma unroll
            for (int j = 0; j < 4; ++j)
                outf[(size_t)(rbase + j) * NDIM + col] = acc[m][n][j] + bval;
        }
    }
}

// ---------------------------------------------------------------------------
// Phase A (MFMA): per-chunk S_local = K^T V (+ z via ones-cols), bf16 out.
// ---------------------------------------------------------------------------
__global__ __launch_bounds__(256) void chunk_sums_mfma(
    const unsigned short* __restrict__ Kt,  // [BH][64][T]
    const unsigned short* __restrict__ Vt,  // [BH][64][T]
    unsigned short* __restrict__ Sl,        // [BH*NC][64*64]
    unsigned short* __restrict__ Zl)        // [BH*NC][64]
{
    const int tid = threadIdx.x, lane = tid & 63, w = tid >> 6;
    const int lo = lane & 15, hi = lane >> 4;
    const int cid = blockIdx.x, bh = cid >> 5, c = cid & 31, t0 = c * CT;
    const unsigned short* kT = Kt + (size_t)bh * 64 * T_ + t0;
    const unsigned short* vT = Vt + (size_t)bh * 64 * T_ + t0;

    const bf16x8 ones8 = {0x3F80, 0x3F80, 0x3F80, 0x3F80,
                          0x3F80, 0x3F80, 0x3F80, 0x3F80};
    f32x4 acc[5] = {};
#pragma unroll
    for (int kt = 0; kt < 4; ++kt) {
        bf16x8 af = *(const bf16x8*)&kT[(size_t)(w * 16 + lo) * T_ + kt * 32 + hi * 8];
        bf16x8 bfr[5];
#pragma unroll
        for (int et = 0; et < 4; ++et)
            bfr[et] = *(const bf16x8*)&vT[(size_t)(et * 16 + lo) * T_ + kt * 32 + hi * 8];
        bfr[4] = ones8;
#pragma unroll
        for (int et = 0; et < 5; ++et)
            acc[et] = __builtin_amdgcn_mfma_f32_16x16x32_bf16(af, bfr[et], acc[et], 0, 0, 0);
    }
    unsigned short* sO = Sl + (size_t)cid * 4096;
    const int d0 = w * 16 + hi * 4;
#pragma unroll
    for (int et = 0; et < 4; ++et) {
        const int e = et * 16 + lo;
        ushort4 pk = make_ushort4(f2bf(acc[et][0]), f2bf(acc[et][1]),
                                  f2bf(acc[et][2]), f2bf(acc[et][3]));
        *(ushort4*)&sO[e * 64 + d0] = pk;
    }
    if (lo == 0) {
        ushort4 pk = make_ushort4(f2bf(acc[4][0]), f2bf(acc[4][1]),
                                  f2bf(acc[4][2]), f2bf(acc[4][3]));
        *(ushort4*)&Zl[(size_t)cid * 64 + d0] = pk;
    }
}

// ---------------------------------------------------------------------------
// Phase B: in-place exclusive prefix over chunks, bf16, f32 accumulation.
// ---------------------------------------------------------------------------
__global__ __launch_bounds__(256) void chunk_scan_bf(
    unsigned short* __restrict__ S, unsigned short* __restrict__ Z)
{
    const int bh = blockIdx.y;
    const int f0 = blockIdx.x * 512 + threadIdx.x * 2;
    float a0 = 0.f, a1 = 0.f;
    unsigned short* base = S + (size_t)bh * NC * 4096 + f0;
    for (int c = 0; c < NC; ++c) {
        uint32_t* p = (uint32_t*)(base + (size_t)c * 4096);
        uint32_t v = *p;
        float c0 = bf2f(v & 0xffffu), c1 = bf2f(v >> 16);
        *p = (uint32_t)f2bf(a0) | ((uint32_t)f2bf(a1) << 16);
        a0 += c0; a1 += c1;
    }
    if (blockIdx.x == 0 && threadIdx.x < 32) {
        float b0 = 0.f, b1 = 0.f;
        unsigned short* zb = Z + (size_t)bh * NC * 64 + threadIdx.x * 2;
        for (int c = 0; c < NC; ++c) {
            uint32_t* p = (uint32_t*)(zb + (size_t)c * 64);
            uint32_t v = *p;
            float c0 = bf2f(v & 0xffffu), c1 = bf2f(v >> 16);
            *p = (uint32_t)f2bf(b0) | ((uint32_t)f2bf(b1) << 16);
            b0 += c0; b1 += c1;
        }
    }
}

// ---------------------------------------------------------------------------
// Phase C (MFMA): P^T = K.Q^T (masked), numext = Q.[Sp|z] + P.[V|1].
// ---------------------------------------------------------------------------
__global__ __launch_bounds__(256) void chunk_attn_mfma(
    const unsigned short* __restrict__ Qb,  // [BH][T][64]
    const unsigned short* __restrict__ Kb,  // [BH][T][64]
    const unsigned short* __restrict__ Vt,  // [BH][64][T]
    const unsigned short* __restrict__ SpT, // [BH*NC][64*64] prefix [e][d]
    const unsigned short* __restrict__ Zp,  // [BH*NC][64] prefix
    unsigned short* __restrict__ att)       // [M][1024]
{
    __shared__ unsigned short lds[128 * 128];

    const int tid = threadIdx.x;
    const int lane = tid & 63;
    const int w = tid >> 6;
    const int lo = lane & 15, hi = lane >> 4;
    const int cid = blockIdx.x;
    const int bh = cid >> 5, c = cid & 31;
    const int t0 = c * CT;

    const unsigned short* qB = Qb + ((size_t)bh * T_ + t0) * 64;
    const unsigned short* kB = Kb + ((size_t)bh * T_ + t0) * 64;
    const unsigned short* vB = Vt + (size_t)bh * 64 * T_ + t0;
    const unsigned short* sB = SpT + (size_t)cid * 4096;
    const unsigned short* zB = Zp + (size_t)cid * 64;

    bf16x8 ka[2][2];
#pragma unroll
    for (int si = 0; si < 2; ++si)
#pragma unroll
        for (int kt = 0; kt < 2; ++kt)
            ka[si][kt] = *(const bf16x8*)&kB[(w * 32 + si * 16 + lo) * 64 + kt * 32 + hi * 8];

    f32x4 pacc[2][8] = {};
#pragma unroll
    for (int ti = 0; ti < 8; ++ti) {
        if (ti >= 2 * w) {
#pragma unroll
            for (int kt = 0; kt < 2; ++kt) {
                bf16x8 qf = *(const bf16x8*)&qB[(ti * 16 + lo) * 64 + kt * 32 + hi * 8];
                pacc[0][ti] = __builtin_amdgcn_mfma_f32_16x16x32_bf16(
                    ka[0][kt], qf, pacc[0][ti], 0, 0, 0);
                if (ti >= 2 * w + 1)
                    pacc[1][ti] = __builtin_amdgcn_mfma_f32_16x16x32_bf16(
                        ka[1][kt], qf, pacc[1][ti], 0, 0, 0);
            }
        }
    }
#pragma unroll
    for (int ti = 0; ti < 8; ++ti) {
        if (ti >= 2 * w) {
            const int t = ti * 16 + lo;
#pragma unroll
            for (int si = 0; si < 2; ++si) {
                const int s0 = w * 32 + si * 16 + hi * 4;
                ushort4 pk;
                unsigned short* pe = (unsigned short*)&pk;
#pragma unroll
                for (int j = 0; j < 4; ++j)
                    pe[j] = (s0 + j <= t) ? f2bf(pacc[si][ti][j]) : (unsigned short)0;
                *(ushort4*)((char*)lds + t * 256 + ((s0 * 2) ^ ((t & 7) << 4))) = pk;
            }
        }
    }
    __syncthreads();

    const bf16x8 ones8 = {0x3F80, 0x3F80, 0x3F80, 0x3F80,
                          0x3F80, 0x3F80, 0x3F80, 0x3F80};
    f32x4 acc[2][5] = {};
#pragma unroll
    for (int kt = 0; kt < 6; ++kt) {
        const int skt = kt - 2;
        if (kt < 2 || skt <= w) {
            bf16x8 bfr[5];
            if (kt < 2) {
#pragma unroll
                for (int et = 0; et < 4; ++et)
                    bfr[et] = *(const bf16x8*)&sB[(et * 16 + lo) * 64 + kt * 32 + hi * 8];
                bfr[4] = *(const bf16x8*)&zB[kt * 32 + hi * 8];
            } else {
#pragma unroll
                for (int et = 0; et < 4; ++et)
                    bfr[et] = *(const bf16x8*)&vB[(size_t)(et * 16 + lo) * T_ + skt * 32 + hi * 8];
                bfr[4] = ones8;
            }
#pragma unroll
            for (int m = 0; m < 2; ++m) {
                const int t = w * 32 + m * 16 + lo;
                bf16x8 af;
                if (kt < 2)
                    af = *(const bf16x8*)&qB[t * 64 + kt * 32 + hi * 8];
                else
                    af = *(const bf16x8*)((char*)lds + t * 256 +
                         (((skt * 32 + hi * 8) * 2) ^ ((t & 7) << 4)));
#pragma unroll
                for (int et = 0; et < 5; ++et)
                    acc[m][et] = __builtin_amdgcn_mfma_f32_16x16x32_bf16(
                        af, bfr[et], acc[m][et], 0, 0, 0);
            }
        }
    }

    __syncthreads();
#pragma unroll
    for (int m = 0; m < 2; ++m) {
#pragma unroll
        for (int j = 0; j < 4; ++j) {
            const int t = w * 32 + m * 16 + hi * 4 + j;
            const float rden = 1.f / (acc[m][4][j] + EPSC);
#pragma unroll
            for (int et = 0; et < 4; ++et) {
                const int e = et * 16 + lo;
                *(unsigned short*)((char*)lds + t * 144 + e * 2) =
                    f2bf(acc[m][et][j] * rden);
            }
        }
    }
    __syncthreads();
    const int b = bh >> 4, h = bh & 15;
#pragma unroll
    for (int r = 0; r < 4; ++r) {
        const int vid = tid + r * 256;
        const int t = vid >> 3, eg = vid & 7;
        uint4 val = *(const uint4*)((const char*)lds + t * 144 + eg * 16);
        *(uint4*)&att[(size_t)(b * T_ + t0 + t) * E_ + h * 64 + eg * 8] = val;
    }
}

// ---------------------------------------------------------------------------
extern "C" void kernel_launch(void* const* d_in, const int* in_sizes, int n_in,
                              void* d_out, int out_size, void* d_ws, size_t ws_size,
                              hipStream_t stream)
{
    const float* x  = (const float*)d_in[0];
    const float* wq = (const float*)d_in[1];
    const float* bq = (const float*)d_in[2];
    const float* wk = (const float*)d_in[3];
    const float* bk = (const float*)d_in[4];
    const float* wv = (const float*)d_in[5];
    const float* bv = (const float*)d_in[6];
    const float* wo = (const float*)d_in[7];
    const float* bo = (const float*)d_in[8];
    float* out = (float*)d_out;

    // workspace layout (MB): qb 0-16 | kb 16-32 | ktb 32-48 | vtb 48-64 |
    //   xb 64-80 (aliased by attb) | Sl 80-88 | Zl 88-88.125 | wT 88.125-96.125
    char* ws = (char*)d_ws;
    unsigned short* qb  = (unsigned short*)(ws);
    unsigned short* kb  = (unsigned short*)(ws + (size_t)16 * 1024 * 1024);
    unsigned short* ktb = (unsigned short*)(ws + (size_t)32 * 1024 * 1024);
    unsigned short* vtb = (unsigned short*)(ws + (size_t)48 * 1024 * 1024);
    unsigned short* xb  = (unsigned short*)(ws + (size_t)64 * 1024 * 1024);
    unsigned short* attb = xb;   // xb dead after QKV GEMM
    unsigned short* Sl  = (unsigned short*)(ws + (size_t)80 * 1024 * 1024);
    unsigned short* Zl  = (unsigned short*)(ws + (size_t)88 * 1024 * 1024);
    unsigned short* wqT = (unsigned short*)(ws + (size_t)88 * 1024 * 1024 + 128 * 1024);
    unsigned short* wkT = wqT + (size_t)KDIM * NDIM;   // contiguous [3072][1024]
    unsigned short* wvT = wkT + (size_t)KDIM * NDIM;
    unsigned short* woT = wvT + (size_t)KDIM * NDIM;

    conv_bf16<<<M_ * KDIM / (256 * 8), 256, 0, stream>>>(x, xb);
    transpose_w4<<<dim3(16, 16, 4), 256, 0, stream>>>(wq, wk, wv, wo,
                                                      wqT, wkT, wvT, woT);

    gemm_qkv_x<<<768, 256, 0, stream>>>(xb, wqT, bq, bk, bv, qb, kb, ktb, vtb);

    chunk_sums_mfma<<<B_ * H_ * NC, 256, 0, stream>>>(ktb, vtb, Sl, Zl);
    chunk_scan_bf<<<dim3(8, B_ * H_), 256, 0, stream>>>(Sl, Zl);
    chunk_attn_mfma<<<B_ * H_ * NC, 256, 0, stream>>>(qb, kb, vtb, Sl, Zl, attb);

    gemm_out<<<512, 256, 0, stream>>>(attb, woT, bo, out);
}

// Round 8
// 170.738 us; speedup vs baseline: 1.2653x; 1.2653x over previous
//
#include <hip/hip_runtime.h>
#include <hip/hip_bf16.h>
#include <cstdint>
#include <cstddef>

// Problem constants
#define B_   2
#define T_   4096
#define E_   1024
#define H_   16
#define D_   64
#define M_   (B_ * T_)       // 8192 rows
#define KDIM 1024
#define NDIM 1024
#define EPSC 1e-6f
#define CT   128             // chunk length
#define NC   (T_ / CT)       // 32 chunks per (b,h)

typedef __attribute__((ext_vector_type(8))) short bf16x8;
typedef __attribute__((ext_vector_type(4))) float f32x4;

// ---------- small helpers ----------
__device__ __forceinline__ float bf2f(uint32_t u) {
    union { uint32_t u; float f; } x; x.u = u << 16; return x.f;
}
__device__ __forceinline__ unsigned short f2bf(float f) {
    union { float f; uint32_t u; } x; x.f = f;
    uint32_t r = x.u + 0x7fffu + ((x.u >> 16) & 1u);   // RNE
    return (unsigned short)(r >> 16);
}
__device__ __forceinline__ void gload16(const void* g, void* l) {
    __builtin_amdgcn_global_load_lds(
        (const __attribute__((address_space(1))) void*)g,
        (__attribute__((address_space(3))) void*)l, 16, 0, 0);
}

// ---------------------------------------------------------------------------
// fp32 -> bf16 bulk convert (x). Each thread: 8 floats.
// ---------------------------------------------------------------------------
__global__ __launch_bounds__(256) void conv_bf16(
    const float* __restrict__ in, unsigned short* __restrict__ out)
{
    const int i = blockIdx.x * 256 + threadIdx.x;
    const float4* p = (const float4*)in;
    float4 a = p[i * 2], b = p[i * 2 + 1];
    ushort4 o0 = make_ushort4(f2bf(a.x), f2bf(a.y), f2bf(a.z), f2bf(a.w));
    ushort4 o1 = make_ushort4(f2bf(b.x), f2bf(b.y), f2bf(b.z), f2bf(b.w));
    *(ushort4*)&out[(size_t)i * 8] = o0;
    *(ushort4*)&out[(size_t)i * 8 + 4] = o1;
}

// ---------------------------------------------------------------------------
// Transpose + convert the four 1024x1024 fp32 weights to bf16 [N][K].
// o0..o2 written contiguously (one [3072][1024] matrix for fused QKV).
// ---------------------------------------------------------------------------
__global__ __launch_bounds__(256) void transpose_w4(
    const float* __restrict__ w0, const float* __restrict__ w1,
    const float* __restrict__ w2, const float* __restrict__ w3,
    unsigned short* __restrict__ o0, unsigned short* __restrict__ o1,
    unsigned short* __restrict__ o2, unsigned short* __restrict__ o3)
{
    const float* src; unsigned short* dst;
    switch (blockIdx.z) {
        case 0: src = w0; dst = o0; break;
        case 1: src = w1; dst = o1; break;
        case 2: src = w2; dst = o2; break;
        default: src = w3; dst = o3; break;
    }
    __shared__ float tile[64][65];
    const int t = threadIdx.x, tx = t & 63, ty = t >> 6;
    const int r0 = blockIdx.y * 64, c0 = blockIdx.x * 64;
#pragma unroll
    for (int i = 0; i < 16; ++i)
        tile[ty + i * 4][tx] = src[(size_t)(r0 + ty + i * 4) * KDIM + c0 + tx];
    __syncthreads();
#pragma unroll
    for (int i = 0; i < 16; ++i)
        dst[(size_t)(c0 + ty + i * 4) * KDIM + r0 + tx] = f2bf(tile[tx][ty + i * 4]);
}

// ---------------------------------------------------------------------------
// Fused QKV GEMM (round-6 proven structure + col-stripe XCD schedule):
//   BM=256, BN=128, BK=64, 8 waves (4Mx2N, 64x64 each), 96 KB double-buffer,
//   counted vmcnt(4), no sched_barrier pins, LDS-staged coalesced epilogue.
//   NEW: XCD cs=orig&7 owns col-tiles {3cs..3cs+2} x all 32 row panels,
//   col-fast order -> B-slice (768 KB) L2-resident, A-panel fetched ~once/XCD.
// ---------------------------------------------------------------------------
__global__ __launch_bounds__(512, 2) void gemm_qkv_p(
    const unsigned short* __restrict__ A,    // [8192][1024] bf16
    const unsigned short* __restrict__ Wt,   // [3072][1024] bf16 (N-major)
    const float* __restrict__ bq, const float* __restrict__ bk,
    const float* __restrict__ bv,
    unsigned short* __restrict__ qb,  unsigned short* __restrict__ kb,
    unsigned short* __restrict__ ktb, unsigned short* __restrict__ vtb)
{
    __shared__ char lds[98304];   // A: 2x32KB @0, B: 2x16KB @64KB

    const int tid  = threadIdx.x;
    const int lane = tid & 63;
    const int w    = tid >> 6;       // 0..7
    const int wm   = w >> 1;         // 0..3 (row quarter, 64 rows)
    const int wn   = w & 1;          // 0..1 (col half, 64 cols)
    const int lo   = lane & 15, hi = lane >> 4;

    // col-stripe XCD mapping: 768 blocks = 8 stripes x (32 rows x 3 cols)
    const int orig = blockIdx.x;
    const int cs = orig & 7;         // XCD / col-stripe
    const int i6 = orig >> 3;        // 0..95
    const int bx = cs * 3 + (i6 % 3);    // 24 col tiles of 128
    const int by = i6 / 3;               // 32 row tiles of 256
    const int row0 = by * 256;
    const int col0 = bx * 128;

    // staging source precompute: per 8KB chunk (64 rows x 128B), dest byte
    // X=tid*16 (linear); logical Y = X ^ (((X>>7)&7)<<4); row=Y>>7,
    // k-elem=(Y&127)>>1.
    int sr, skE;
    { int X = tid * 16; int Y = X ^ (((X >> 7) & 7) << 4);
      sr = Y >> 7; skE = (Y & 127) >> 1; }
    const unsigned short* pa = A  + (size_t)(row0 + sr) * KDIM + skE;
    const unsigned short* pb = Wt + (size_t)(col0 + sr) * KDIM + skE;

#define BUFA(p) (lds + (p) * 32768)
#define BUFB(p) (lds + 65536 + (p) * 16384)
#define STGA(t) { char* d_ = BUFA((t) & 1) + tid * 16;                        \
    _Pragma("unroll") for (int ch = 0; ch < 4; ++ch)                          \
        gload16(pa + (size_t)ch * 64 * KDIM + (t) * 64, d_ + ch * 8192); }
#define STGB(t) { char* d_ = BUFB((t) & 1) + tid * 16;                        \
    _Pragma("unroll") for (int ch = 0; ch < 2; ++ch)                          \
        gload16(pb + (size_t)ch * 64 * KDIM + (t) * 64, d_ + ch * 8192); }

    // ds_read frag offsets: logical col-byte (kk*64 + hi*16) XOR ((row&7)<<4),
    // row&7 == lane&7 for all fragment rows (bases are multiples of 16).
    const int koff0 = (hi * 16)       ^ ((lane & 7) << 4);
    const int koff1 = (64 + hi * 16)  ^ ((lane & 7) << 4);

    f32x4 acc[4][4] = {};
    const int NT = KDIM / 64;        // 16 K-tiles

    // prologue: A(0),B(0),A(1) in flight (10 loads); vmcnt(4) -> A0,B0 landed
    STGA(0); STGB(0); STGA(1);
    asm volatile("s_waitcnt vmcnt(4)" ::: "memory");
    __builtin_amdgcn_s_barrier();

#pragma unroll 2
    for (int t = 0; t < NT; ++t) {
        const char* bA = BUFA(t & 1);
        const char* bB = BUFB(t & 1);

        if (t + 1 < NT) STGB(t + 1);   // into bufB[o] (reads retired at t-1 mid)

        bf16x8 af[4][2], bfr[4][2];
#pragma unroll
        for (int m = 0; m < 4; ++m) {
            const char* p = bA + (wm * 64 + m * 16 + lo) * 128;
            af[m][0] = *(const bf16x8*)(p + koff0);
            af[m][1] = *(const bf16x8*)(p + koff1);
        }
#pragma unroll
        for (int n = 0; n < 4; ++n) {
            const char* p = bB + (wn * 64 + n * 16 + lo) * 128;
            bfr[n][0] = *(const bf16x8*)(p + koff0);
            bfr[n][1] = *(const bf16x8*)(p + koff1);
        }
        __builtin_amdgcn_s_setprio(1);
#pragma unroll
        for (int kk = 0; kk < 2; ++kk)
#pragma unroll
            for (int m = 0; m < 4; ++m)
#pragma unroll
                for (int n = 0; n < 4; ++n)
                    acc[m][n] = __builtin_amdgcn_mfma_f32_16x16x32_bf16(
                        af[m][kk], bfr[n][kk], acc[m][n], 0, 0, 0);
        __builtin_amdgcn_s_setprio(0);

        // mid: all my ds_reads landed (lgkm0) -> after barrier, restage is safe
        asm volatile("s_waitcnt lgkmcnt(0)" ::: "memory");
        __builtin_amdgcn_s_barrier();

        if (t + 2 < NT) {
            STGA(t + 2);               // into bufA[c] (its reads just retired)
            asm volatile("s_waitcnt vmcnt(4)" ::: "memory");  // A(t+1),B(t+1) in
        } else {
            asm volatile("s_waitcnt vmcnt(0)" ::: "memory");
        }
        __builtin_amdgcn_s_barrier();
    }
#undef STGA
#undef STGB
#undef BUFA
#undef BUFB

    // ---- epilogue: frags -> padded LDS tile, then coalesced 16B stores ----
    // C/D mapping: col=lane&15, row=(lane>>4)*4+j  [m89/m91 verified]
    unsigned short* ep = (unsigned short*)lds;   // [256][136] bf16, 69.6 KB
    const int matid = bx >> 3;                   // 0=Q 1=K 2=V
    const float* bias = (matid == 0) ? bq : (matid == 1) ? bk : bv;
#pragma unroll
    for (int n = 0; n < 4; ++n) {
        const int lcol = wn * 64 + n * 16 + lo;
        const float bval = bias[(bx & 7) * 128 + lcol];
#pragma unroll
        for (int m = 0; m < 4; ++m) {
            const int lr0 = wm * 64 + m * 16 + hi * 4;
#pragma unroll
            for (int j = 0; j < 4; ++j) {
                float v = acc[m][n][j] + bval;
                if (matid <= 1) v = (v > 0.f) ? (v + 1.f) : __expf(v);
                ep[(lr0 + j) * 136 + lcol] = f2bf(v);
            }
        }
    }
    __syncthreads();

    const int b   = row0 >> 12;          // batch
    const int tg0 = row0 & (T_ - 1);     // t-offset within batch
    const int h0  = (bx & 7) * 2;        // first head of this col-tile

    if (matid <= 1) {                    // row-major out: qb or kb  [B,H,T,D]
        unsigned short* dst0 = (matid == 0) ? qb : kb;
#pragma unroll
        for (int it = 0; it < 8; ++it) {
            const int vid = it * 512 + tid;       // 0..4095
            const int head = vid >> 11;
            const int rem = vid & 2047;
            const int tr = rem >> 3, c8 = rem & 7;
            uint4 v = *(const uint4*)&ep[tr * 136 + head * 64 + c8 * 8];
            *(uint4*)&dst0[((size_t)((b * H_ + h0 + head) * T_) + tg0 + tr) * D_
                           + c8 * 8] = v;
        }
    }
    if (matid >= 1) {                    // transposed out: ktb or vtb [B,H,D,T]
        unsigned short* dstT = (matid == 1) ? ktb : vtb;
#pragma unroll
        for (int it = 0; it < 8; ++it) {
            const int vid = it * 512 + tid;
            const int head = vid >> 11;
            const int rem = vid & 2047;
            const int d = rem & 63, t8 = rem >> 6;    // d fast -> LDS conflict-free
            unsigned short vals[8];
#pragma unroll
            for (int i = 0; i < 8; ++i)
                vals[i] = ep[(t8 * 8 + i) * 136 + head * 64 + d];
            *(uint4*)&dstT[((size_t)((b * H_ + h0 + head) * D_) + d) * T_
                           + tg0 + t8 * 8] = *(const uint4*)vals;
        }
    }
}

// ---------------------------------------------------------------------------
// Output projection GEMM, same 8-wave pipelined structure:
//   BM=256, BN=128, BK=64, grid 8x32 = 256 blocks (exactly one full round);
//   XCD cs=orig&7 owns col-tile cs (B-slice 256 KB L2-resident).
//   Direct f32 epilogue (natural row-major).
// ---------------------------------------------------------------------------
__global__ __launch_bounds__(512, 2) void gemm_out_p(
    const unsigned short* __restrict__ A,   // attb [8192][1024] bf16
    const unsigned short* __restrict__ Bt,  // woT [1024][1024] bf16
    const float* __restrict__ bias, float* __restrict__ outf)
{
    __shared__ char lds[98304];

    const int tid  = threadIdx.x;
    const int lane = tid & 63;
    const int w    = tid >> 6;
    const int wm   = w >> 1;
    const int wn   = w & 1;
    const int lo   = lane & 15, hi = lane >> 4;

    const int orig = blockIdx.x;     // 256 blocks
    const int bx = orig & 7;         // col tile (XCD-resident B slice)
    const int by = orig >> 3;        // row tile
    const int row0 = by * 256;
    const int col0 = bx * 128;

    int sr, skE;
    { int X = tid * 16; int Y = X ^ (((X >> 7) & 7) << 4);
      sr = Y >> 7; skE = (Y & 127) >> 1; }
    const unsigned short* pa = A  + (size_t)(row0 + sr) * KDIM + skE;
    const unsigned short* pb = Bt + (size_t)(col0 + sr) * KDIM + skE;

#define BUFA(p) (lds + (p) * 32768)
#define BUFB(p) (lds + 65536 + (p) * 16384)
#define STGA(t) { char* d_ = BUFA((t) & 1) + tid * 16;                        \
    _Pragma("unroll") for (int ch = 0; ch < 4; ++ch)                          \
        gload16(pa + (size_t)ch * 64 * KDIM + (t) * 64, d_ + ch * 8192); }
#define STGB(t) { char* d_ = BUFB((t) & 1) + tid * 16;                        \
    _Pragma("unroll") for (int ch = 0; ch < 2; ++ch)                          \
        gload16(pb + (size_t)ch * 64 * KDIM + (t) * 64, d_ + ch * 8192); }

    const int koff0 = (hi * 16)       ^ ((lane & 7) << 4);
    const int koff1 = (64 + hi * 16)  ^ ((lane & 7) << 4);

    f32x4 acc[4][4] = {};
    const int NT = KDIM / 64;

    STGA(0); STGB(0); STGA(1);
    asm volatile("s_waitcnt vmcnt(4)" ::: "memory");
    __builtin_amdgcn_s_barrier();

#pragma unroll 2
    for (int t = 0; t < NT; ++t) {
        const char* bA = BUFA(t & 1);
        const char* bB = BUFB(t & 1);

        if (t + 1 < NT) STGB(t + 1);

        bf16x8 af[4][2], bfr[4][2];
#pragma unroll
        for (int m = 0; m < 4; ++m) {
            const char* p = bA + (wm * 64 + m * 16 + lo) * 128;
            af[m][0] = *(const bf16x8*)(p + koff0);
            af[m][1] = *(const bf16x8*)(p + koff1);
        }
#pragma unroll
        for (int n = 0; n < 4; ++n) {
            const char* p = bB + (wn * 64 + n * 16 + lo) * 128;
            bfr[n][0] = *(const bf16x8*)(p + koff0);
            bfr[n][1] = *(const bf16x8*)(p + koff1);
        }
        __builtin_amdgcn_s_setprio(1);
#pragma unroll
        for (int kk = 0; kk < 2; ++kk)
#pragma unroll
            for (int m = 0; m < 4; ++m)
#pragma unroll
                for (int n = 0; n < 4; ++n)
                    acc[m][n] = __builtin_amdgcn_mfma_f32_16x16x32_bf16(
                        af[m][kk], bfr[n][kk], acc[m][n], 0, 0, 0);
        __builtin_amdgcn_s_setprio(0);

        asm volatile("s_waitcnt lgkmcnt(0)" ::: "memory");
        __builtin_amdgcn_s_barrier();

        if (t + 2 < NT) {
            STGA(t + 2);
            asm volatile("s_waitcnt vmcnt(4)" ::: "memory");
        } else {
            asm volatile("s_waitcnt vmcnt(0)" ::: "memory");
        }
        __builtin_amdgcn_s_barrier();
    }
#undef STGA
#undef STGB
#undef BUFA
#undef BUFB

    // direct f32 epilogue: C/D mapping col=lane&15, row=(lane>>4)*4+j
#pragma unroll
    for (int n = 0; n < 4; ++n) {
        const int col = col0 + wn * 64 + n * 16 + lo;
        const float bval = bias[col];
#pragma unroll
        for (int m = 0; m < 4; ++m) {
            const int rbase = row0 + wm * 64 + m * 16 + hi * 4;
#pragma unroll
            for (int j = 0; j < 4; ++j)
                outf[(size_t)(rbase + j) * NDIM + col] = acc[m][n][j] + bval;
        }
    }
}

// ---------------------------------------------------------------------------
// Phase A (MFMA): per-chunk S_local = K^T V (+ z via ones-cols), bf16 out.
// ---------------------------------------------------------------------------
__global__ __launch_bounds__(256) void chunk_sums_mfma(
    const unsigned short* __restrict__ Kt,  // [BH][64][T]
    const unsigned short* __restrict__ Vt,  // [BH][64][T]
    unsigned short* __restrict__ Sl,        // [BH*NC][64*64]
    unsigned short* __restrict__ Zl)        // [BH*NC][64]
{
    const int tid = threadIdx.x, lane = tid & 63, w = tid >> 6;
    const int lo = lane & 15, hi = lane >> 4;
    const int cid = blockIdx.x, bh = cid >> 5, c = cid & 31, t0 = c * CT;
    const unsigned short* kT = Kt + (size_t)bh * 64 * T_ + t0;
    const unsigned short* vT = Vt + (size_t)bh * 64 * T_ + t0;

    const bf16x8 ones8 = {0x3F80, 0x3F80, 0x3F80, 0x3F80,
                          0x3F80, 0x3F80, 0x3F80, 0x3F80};
    f32x4 acc[5] = {};
#pragma unroll
    for (int kt = 0; kt < 4; ++kt) {
        bf16x8 af = *(const bf16x8*)&kT[(size_t)(w * 16 + lo) * T_ + kt * 32 + hi * 8];
        bf16x8 bfr[5];
#pragma unroll
        for (int et = 0; et < 4; ++et)
            bfr[et] = *(const bf16x8*)&vT[(size_t)(et * 16 + lo) * T_ + kt * 32 + hi * 8];
        bfr[4] = ones8;
#pragma unroll
        for (int et = 0; et < 5; ++et)
            acc[et] = __builtin_amdgcn_mfma_f32_16x16x32_bf16(af, bfr[et], acc[et], 0, 0, 0);
    }
    unsigned short* sO = Sl + (size_t)cid * 4096;
    const int d0 = w * 16 + hi * 4;
#pragma unroll
    for (int et = 0; et < 4; ++et) {
        const int e = et * 16 + lo;
        ushort4 pk = make_ushort4(f2bf(acc[et][0]), f2bf(acc[et][1]),
                                  f2bf(acc[et][2]), f2bf(acc[et][3]));
        *(ushort4*)&sO[e * 64 + d0] = pk;
    }
    if (lo == 0) {
        ushort4 pk = make_ushort4(f2bf(acc[4][0]), f2bf(acc[4][1]),
                                  f2bf(acc[4][2]), f2bf(acc[4][3]));
        *(ushort4*)&Zl[(size_t)cid * 64 + d0] = pk;
    }
}

// ---------------------------------------------------------------------------
// Phase B: in-place exclusive prefix over chunks, bf16, f32 accumulation.
// ---------------------------------------------------------------------------
__global__ __launch_bounds__(256) void chunk_scan_bf(
    unsigned short* __restrict__ S, unsigned short* __restrict__ Z)
{
    const int bh = blockIdx.y;
    const int f0 = blockIdx.x * 512 + threadIdx.x * 2;
    float a0 = 0.f, a1 = 0.f;
    unsigned short* base = S + (size_t)bh * NC * 4096 + f0;
    for (int c = 0; c < NC; ++c) {
        uint32_t* p = (uint32_t*)(base + (size_t)c * 4096);
        uint32_t v = *p;
        float c0 = bf2f(v & 0xffffu), c1 = bf2f(v >> 16);
        *p = (uint32_t)f2bf(a0) | ((uint32_t)f2bf(a1) << 16);
        a0 += c0; a1 += c1;
    }
    if (blockIdx.x == 0 && threadIdx.x < 32) {
        float b0 = 0.f, b1 = 0.f;
        unsigned short* zb = Z + (size_t)bh * NC * 64 + threadIdx.x * 2;
        for (int c = 0; c < NC; ++c) {
            uint32_t* p = (uint32_t*)(zb + (size_t)c * 64);
            uint32_t v = *p;
            float c0 = bf2f(v & 0xffffu), c1 = bf2f(v >> 16);
            *p = (uint32_t)f2bf(b0) | ((uint32_t)f2bf(b1) << 16);
            b0 += c0; b1 += c1;
        }
    }
}

// ---------------------------------------------------------------------------
// Phase C (MFMA): P^T = K.Q^T (masked), numext = Q.[Sp|z] + P.[V|1].
// ---------------------------------------------------------------------------
__global__ __launch_bounds__(256) void chunk_attn_mfma(
    const unsigned short* __restrict__ Qb,  // [BH][T][64]
    const unsigned short* __restrict__ Kb,  // [BH][T][64]
    const unsigned short* __restrict__ Vt,  // [BH][64][T]
    const unsigned short* __restrict__ SpT, // [BH*NC][64*64] prefix [e][d]
    const unsigned short* __restrict__ Zp,  // [BH*NC][64] prefix
    unsigned short* __restrict__ att)       // [M][1024]
{
    __shared__ unsigned short lds[128 * 128];

    const int tid = threadIdx.x;
    const int lane = tid & 63;
    const int w = tid >> 6;
    const int lo = lane & 15, hi = lane >> 4;
    const int cid = blockIdx.x;
    const int bh = cid >> 5, c = cid & 31;
    const int t0 = c * CT;

    const unsigned short* qB = Qb + ((size_t)bh * T_ + t0) * 64;
    const unsigned short* kB = Kb + ((size_t)bh * T_ + t0) * 64;
    const unsigned short* vB = Vt + (size_t)bh * 64 * T_ + t0;
    const unsigned short* sB = SpT + (size_t)cid * 4096;
    const unsigned short* zB = Zp + (size_t)cid * 64;

    bf16x8 ka[2][2];
#pragma unroll
    for (int si = 0; si < 2; ++si)
#pragma unroll
        for (int kt = 0; kt < 2; ++kt)
            ka[si][kt] = *(const bf16x8*)&kB[(w * 32 + si * 16 + lo) * 64 + kt * 32 + hi * 8];

    f32x4 pacc[2][8] = {};
#pragma unroll
    for (int ti = 0; ti < 8; ++ti) {
        if (ti >= 2 * w) {
#pragma unroll
            for (int kt = 0; kt < 2; ++kt) {
                bf16x8 qf = *(const bf16x8*)&qB[(ti * 16 + lo) * 64 + kt * 32 + hi * 8];
                pacc[0][ti] = __builtin_amdgcn_mfma_f32_16x16x32_bf16(
                    ka[0][kt], qf, pacc[0][ti], 0, 0, 0);
                if (ti >= 2 * w + 1)
                    pacc[1][ti] = __builtin_amdgcn_mfma_f32_16x16x32_bf16(
                        ka[1][kt], qf, pacc[1][ti], 0, 0, 0);
            }
        }
    }
#pragma unroll
    for (int ti = 0; ti < 8; ++ti) {
        if (ti >= 2 * w) {
            const int t = ti * 16 + lo;
#pragma unroll
            for (int si = 0; si < 2; ++si) {
                const int s0 = w * 32 + si * 16 + hi * 4;
                ushort4 pk;
                unsigned short* pe = (unsigned short*)&pk;
#pragma unroll
                for (int j = 0; j < 4; ++j)
                    pe[j] = (s0 + j <= t) ? f2bf(pacc[si][ti][j]) : (unsigned short)0;
                *(ushort4*)((char*)lds + t * 256 + ((s0 * 2) ^ ((t & 7) << 4))) = pk;
            }
        }
    }
    __syncthreads();

    const bf16x8 ones8 = {0x3F80, 0x3F80, 0x3F80, 0x3F80,
                          0x3F80, 0x3F80, 0x3F80, 0x3F80};
    f32x4 acc[2][5] = {};
#pragma unroll
    for (int kt = 0; kt < 6; ++kt) {
        const int skt = kt - 2;
        if (kt < 2 || skt <= w) {
            bf16x8 bfr[5];
            if (kt < 2) {
#pragma unroll
                for (int et = 0; et < 4; ++et)
                    bfr[et] = *(const bf16x8*)&sB[(et * 16 + lo) * 64 + kt * 32 + hi * 8];
                bfr[4] = *(const bf16x8*)&zB[kt * 32 + hi * 8];
            } else {
#pragma unroll
                for (int et = 0; et < 4; ++et)
                    bfr[et] = *(const bf16x8*)&vB[(size_t)(et * 16 + lo) * T_ + skt * 32 + hi * 8];
                bfr[4] = ones8;
            }
#pragma unroll
            for (int m = 0; m < 2; ++m) {
                const int t = w * 32 + m * 16 + lo;
                bf16x8 af;
                if (kt < 2)
                    af = *(const bf16x8*)&qB[t * 64 + kt * 32 + hi * 8];
                else
                    af = *(const bf16x8*)((char*)lds + t * 256 +
                         (((skt * 32 + hi * 8) * 2) ^ ((t & 7) << 4)));
#pragma unroll
                for (int et = 0; et < 5; ++et)
                    acc[m][et] = __builtin_amdgcn_mfma_f32_16x16x32_bf16(
                        af, bfr[et], acc[m][et], 0, 0, 0);
            }
        }
    }

    __syncthreads();
#pragma unroll
    for (int m = 0; m < 2; ++m) {
#pragma unroll
        for (int j = 0; j < 4; ++j) {
            const int t = w * 32 + m * 16 + hi * 4 + j;
            const float rden = 1.f / (acc[m][4][j] + EPSC);
#pragma unroll
            for (int et = 0; et < 4; ++et) {
                const int e = et * 16 + lo;
                *(unsigned short*)((char*)lds + t * 144 + e * 2) =
                    f2bf(acc[m][et][j] * rden);
            }
        }
    }
    __syncthreads();
    const int b = bh >> 4, h = bh & 15;
#pragma unroll
    for (int r = 0; r < 4; ++r) {
        const int vid = tid + r * 256;
        const int t = vid >> 3, eg = vid & 7;
        uint4 val = *(const uint4*)((const char*)lds + t * 144 + eg * 16);
        *(uint4*)&att[(size_t)(b * T_ + t0 + t) * E_ + h * 64 + eg * 8] = val;
    }
}

// ---------------------------------------------------------------------------
extern "C" void kernel_launch(void* const* d_in, const int* in_sizes, int n_in,
                              void* d_out, int out_size, void* d_ws, size_t ws_size,
                              hipStream_t stream)
{
    const float* x  = (const float*)d_in[0];
    const float* wq = (const float*)d_in[1];
    const float* bq = (const float*)d_in[2];
    const float* wk = (const float*)d_in[3];
    const float* bk = (const float*)d_in[4];
    const float* wv = (const float*)d_in[5];
    const float* bv = (const float*)d_in[6];
    const float* wo = (const float*)d_in[7];
    const float* bo = (const float*)d_in[8];
    float* out = (float*)d_out;

    // workspace layout (MB): qb 0-16 | kb 16-32 | ktb 32-48 | vtb 48-64 |
    //   xb 64-80 (aliased by attb) | Sl 80-88 | Zl 88-88.125 | wT 88.125-96.125
    char* ws = (char*)d_ws;
    unsigned short* qb  = (unsigned short*)(ws);
    unsigned short* kb  = (unsigned short*)(ws + (size_t)16 * 1024 * 1024);
    unsigned short* ktb = (unsigned short*)(ws + (size_t)32 * 1024 * 1024);
    unsigned short* vtb = (unsigned short*)(ws + (size_t)48 * 1024 * 1024);
    unsigned short* xb  = (unsigned short*)(ws + (size_t)64 * 1024 * 1024);
    unsigned short* attb = xb;   // xb dead after QKV GEMM
    unsigned short* Sl  = (unsigned short*)(ws + (size_t)80 * 1024 * 1024);
    unsigned short* Zl  = (unsigned short*)(ws + (size_t)88 * 1024 * 1024);
    unsigned short* wqT = (unsigned short*)(ws + (size_t)88 * 1024 * 1024 + 128 * 1024);
    unsigned short* wkT = wqT + (size_t)KDIM * NDIM;   // contiguous [3072][1024]
    unsigned short* wvT = wkT + (size_t)KDIM * NDIM;
    unsigned short* woT = wvT + (size_t)KDIM * NDIM;

    conv_bf16<<<M_ * KDIM / (256 * 8), 256, 0, stream>>>(x, xb);
    transpose_w4<<<dim3(16, 16, 4), 256, 0, stream>>>(wq, wk, wv, wo,
                                                      wqT, wkT, wvT, woT);

    gemm_qkv_p<<<768, 512, 0, stream>>>(xb, wqT, bq, bk, bv, qb, kb, ktb, vtb);

    chunk_sums_mfma<<<B_ * H_ * NC, 256, 0, stream>>>(ktb, vtb, Sl, Zl);
    chunk_scan_bf<<<dim3(8, B_ * H_), 256, 0, stream>>>(Sl, Zl);
    chunk_attn_mfma<<<B_ * H_ * NC, 256, 0, stream>>>(qb, kb, vtb, Sl, Zl, attb);

    gemm_out_p<<<256, 512, 0, stream>>>(attb, woT, bo, out);
}

// Round 9
// 165.676 us; speedup vs baseline: 1.3039x; 1.0306x over previous
//
#include <hip/hip_runtime.h>
#include <hip/hip_bf16.h>
#include <cstdint>
#include <cstddef>

// Problem constants
#define B_   2
#define T_   4096
#define E_   1024
#define H_   16
#define D_   64
#define M_   (B_ * T_)       // 8192 rows
#define KDIM 1024
#define NDIM 1024
#define EPSC 1e-6f
#define CT   128             // chunk length
#define NC   (T_ / CT)       // 32 chunks per (b,h)

typedef __attribute__((ext_vector_type(8))) short bf16x8;
typedef __attribute__((ext_vector_type(4))) float f32x4;

// ---------- small helpers ----------
__device__ __forceinline__ float bf2f(uint32_t u) {
    union { uint32_t u; float f; } x; x.u = u << 16; return x.f;
}
__device__ __forceinline__ unsigned short f2bf(float f) {
    union { float f; uint32_t u; } x; x.f = f;
    uint32_t r = x.u + 0x7fffu + ((x.u >> 16) & 1u);   // RNE
    return (unsigned short)(r >> 16);
}
__device__ __forceinline__ void gload16(const void* g, void* l) {
    __builtin_amdgcn_global_load_lds(
        (const __attribute__((address_space(1))) void*)g,
        (__attribute__((address_space(3))) void*)l, 16, 0, 0);
}

// ---------------------------------------------------------------------------
// Prep: z<4 -> transpose+convert weight z to bf16 [N][K] (wq/wk/wv contiguous
// for fused QKV); z==4 -> bulk convert x to bf16 (grid-strided).
// ---------------------------------------------------------------------------
__global__ __launch_bounds__(256) void prep(
    const float* __restrict__ x, unsigned short* __restrict__ xb,
    const float* __restrict__ w0, const float* __restrict__ w1,
    const float* __restrict__ w2, const float* __restrict__ w3,
    unsigned short* __restrict__ o0, unsigned short* __restrict__ o1,
    unsigned short* __restrict__ o2, unsigned short* __restrict__ o3)
{
    const int t = threadIdx.x;
    if (blockIdx.z == 4) {
        // convert 8M floats: 256 blocks x 256 threads x 16 iters x 8 floats
        const int bi = blockIdx.y * 16 + blockIdx.x;
        const float4* p = (const float4*)x;
#pragma unroll
        for (int j = 0; j < 16; ++j) {
            const int i = bi * 256 + t + j * 65536;
            float4 a = p[i * 2], b = p[i * 2 + 1];
            ushort4 q0 = make_ushort4(f2bf(a.x), f2bf(a.y), f2bf(a.z), f2bf(a.w));
            ushort4 q1 = make_ushort4(f2bf(b.x), f2bf(b.y), f2bf(b.z), f2bf(b.w));
            *(ushort4*)&xb[(size_t)i * 8] = q0;
            *(ushort4*)&xb[(size_t)i * 8 + 4] = q1;
        }
        return;
    }
    const float* src; unsigned short* dst;
    switch (blockIdx.z) {
        case 0: src = w0; dst = o0; break;
        case 1: src = w1; dst = o1; break;
        case 2: src = w2; dst = o2; break;
        default: src = w3; dst = o3; break;
    }
    __shared__ float tile[64][65];
    const int tx = t & 63, ty = t >> 6;
    const int r0 = blockIdx.y * 64, c0 = blockIdx.x * 64;
#pragma unroll
    for (int i = 0; i < 16; ++i)
        tile[ty + i * 4][tx] = src[(size_t)(r0 + ty + i * 4) * KDIM + c0 + tx];
    __syncthreads();
#pragma unroll
    for (int i = 0; i < 16; ++i)
        dst[(size_t)(c0 + ty + i * 4) * KDIM + r0 + tx] = f2bf(tile[tx][ty + i * 4]);
}

// ---------------------------------------------------------------------------
// Triple-buffered GEMM, minimal-sync schedule:
//   BM=256, BN=128, BK=64, 8 waves (4Mx2N, 64x64 each), 144 KB LDS (3 bufs).
//   Per K-tile: {stage tile t+2 -> 16 ds_read -> 32 MFMA (compiler-ordered)
//   -> vmcnt(6) -> lgkm0 -> ONE barrier}. No mid-barriers, no drains until
//   the last two tiles. XOR swizzle via pre-swizzled global sources.
// MODE 0: fused QKV (grid 768 = 3 full rounds, row-chunked XCD swizzle);
//         LDS-staged epilogue -> qb/kb row-major + ktb/vtb transposed.
// MODE 1: out-projection (grid 256 = 1 round); direct f32 epilogue.
// ---------------------------------------------------------------------------
template <int MODE>
__global__ __launch_bounds__(512, 1) void gemm_tb(
    const unsigned short* __restrict__ A,    // [8192][1024] bf16
    const unsigned short* __restrict__ Wt,   // [N][1024] bf16 (N-major)
    const float* __restrict__ bq, const float* __restrict__ bk,
    const float* __restrict__ bv,
    unsigned short* __restrict__ qb,  unsigned short* __restrict__ kb,
    unsigned short* __restrict__ ktb, unsigned short* __restrict__ vtb,
    float* __restrict__ outf)
{
    __shared__ char lds[147456];   // A: 3x32KB @0, B: 3x16KB @96KB

    const int tid  = threadIdx.x;
    const int lane = tid & 63;
    const int w    = tid >> 6;       // 0..7
    const int wm   = w >> 1;         // 0..3 (row quarter, 64 rows)
    const int wn   = w & 1;          // 0..1 (col half, 64 cols)
    const int lo   = lane & 15, hi = lane >> 4;

    int bx, by;
    if (MODE == 0) {
        // row-chunked XCD swizzle (R6-proven): 768 blocks, 768 % 8 == 0
        const int orig = blockIdx.x;
        const int swz  = (orig & 7) * 96 + (orig >> 3);
        bx = swz % 24;               // 24 col tiles (0-7 Q, 8-15 K, 16-23 V)
        by = swz / 24;               // 32 row tiles
    } else {
        const int orig = blockIdx.x; // 256 blocks
        bx = orig & 7;               // 8 col tiles
        by = orig >> 3;              // 32 row tiles
    }
    const int row0 = by * 256;
    const int col0 = bx * 128;

    // pre-swizzled staging sources: per 8KB chunk (64 rows x 128B), dest byte
    // X=tid*16 (linear); logical Y = X ^ (((X>>7)&7)<<4); row=Y>>7,
    // k-elem=(Y&127)>>1.
    int sr, skE;
    { int X = tid * 16; int Y = X ^ (((X >> 7) & 7) << 4);
      sr = Y >> 7; skE = (Y & 127) >> 1; }
    const unsigned short* pa = A  + (size_t)(row0 + sr) * KDIM + skE;
    const unsigned short* pb = Wt + (size_t)(col0 + sr) * KDIM + skE;

#define STG(t, da, db) {                                                      \
    { char* d_ = (da) + tid * 16;                                             \
      _Pragma("unroll") for (int ch = 0; ch < 4; ++ch)                        \
        gload16(pa + (size_t)ch * 64 * KDIM + (t) * 64, d_ + ch * 8192); }    \
    { char* d_ = (db) + tid * 16;                                             \
      _Pragma("unroll") for (int ch = 0; ch < 2; ++ch)                        \
        gload16(pb + (size_t)ch * 64 * KDIM + (t) * 64, d_ + ch * 8192); } }

    // ds_read frag offsets: logical col-byte (kk*64 + hi*16) XOR ((row&7)<<4),
    // row&7 == lane&7 for all fragment rows (bases are multiples of 16).
    const int koff0 = (hi * 16)       ^ ((lane & 7) << 4);
    const int koff1 = (64 + hi * 16)  ^ ((lane & 7) << 4);

    f32x4 acc[4][4] = {};
    const int NT = KDIM / 64;        // 16 K-tiles

    // rotating buffer pointers (no runtime-indexed arrays -> stay in SGPRs)
    char* pA0 = lds;           char* pB0 = lds + 98304;
    char* pA1 = lds + 32768;   char* pB1 = lds + 114688;
    char* pA2 = lds + 65536;   char* pB2 = lds + 131072;

    // prologue: tiles 0,1 in flight (12 loads); vmcnt(6) -> tile 0 landed
    STG(0, pA0, pB0);
    STG(1, pA1, pB1);
    asm volatile("s_waitcnt vmcnt(6)" ::: "memory");
    __builtin_amdgcn_s_barrier();

    for (int t = 0; t < NT; ++t) {
        if (t + 2 < NT) STG(t + 2, pA2, pB2);   // buf of tile t-1: reads retired

        bf16x8 af[4][2], bfr[4][2];
#pragma unroll
        for (int m = 0; m < 4; ++m) {
            const char* p = pA0 + (wm * 64 + m * 16 + lo) * 128;
            af[m][0] = *(const bf16x8*)(p + koff0);
            af[m][1] = *(const bf16x8*)(p + koff1);
        }
#pragma unroll
        for (int n = 0; n < 4; ++n) {
            const char* p = pB0 + (wn * 64 + n * 16 + lo) * 128;
            bfr[n][0] = *(const bf16x8*)(p + koff0);
            bfr[n][1] = *(const bf16x8*)(p + koff1);
        }
        __builtin_amdgcn_s_setprio(1);
#pragma unroll
        for (int kk = 0; kk < 2; ++kk)
#pragma unroll
            for (int m = 0; m < 4; ++m)
#pragma unroll
                for (int n = 0; n < 4; ++n)
                    acc[m][n] = __builtin_amdgcn_mfma_f32_16x16x32_bf16(
                        af[m][kk], bfr[n][kk], acc[m][n], 0, 0, 0);
        __builtin_amdgcn_s_setprio(0);

        // single sync point per K-tile: t+1 landed (counted), my reads done
        if (t + 2 < NT) { asm volatile("s_waitcnt vmcnt(6)" ::: "memory"); }
        else            { asm volatile("s_waitcnt vmcnt(0)" ::: "memory"); }
        asm volatile("s_waitcnt lgkmcnt(0)" ::: "memory");
        __builtin_amdgcn_s_barrier();

        char* ta = pA0; pA0 = pA1; pA1 = pA2; pA2 = ta;
        char* tb = pB0; pB0 = pB1; pB1 = pB2; pB2 = tb;
    }
#undef STG

    if (MODE == 1) {
        // direct f32 epilogue: C/D mapping col=lane&15, row=(lane>>4)*4+j
#pragma unroll
        for (int n = 0; n < 4; ++n) {
            const int col = col0 + wn * 64 + n * 16 + lo;
            const float bval = bq[col];
#pragma unroll
            for (int m = 0; m < 4; ++m) {
                const int rbase = row0 + wm * 64 + m * 16 + hi * 4;
#pragma unroll
                for (int j = 0; j < 4; ++j)
                    outf[(size_t)(rbase + j) * NDIM + col] = acc[m][n][j] + bval;
            }
        }
        return;
    }

    // ---- QKV epilogue: frags -> padded LDS tile, then coalesced stores ----
    unsigned short* ep = (unsigned short*)lds;   // [256][136] bf16, 69.6 KB
    const int matid = bx >> 3;                   // 0=Q 1=K 2=V
    const float* bias = (matid == 0) ? bq : (matid == 1) ? bk : bv;
#pragma unroll
    for (int n = 0; n < 4; ++n) {
        const int lcol = wn * 64 + n * 16 + lo;
        const float bval = bias[(bx & 7) * 128 + lcol];
#pragma unroll
        for (int m = 0; m < 4; ++m) {
            const int lr0 = wm * 64 + m * 16 + hi * 4;
#pragma unroll
            for (int j = 0; j < 4; ++j) {
                float v = acc[m][n][j] + bval;
                if (matid <= 1) v = (v > 0.f) ? (v + 1.f) : __expf(v);
                ep[(lr0 + j) * 136 + lcol] = f2bf(v);
            }
        }
    }
    __syncthreads();

    const int b   = row0 >> 12;          // batch
    const int tg0 = row0 & (T_ - 1);     // t-offset within batch
    const int h0  = (bx & 7) * 2;        // first head of this col-tile

    if (matid <= 1) {                    // row-major out: qb or kb  [B,H,T,D]
        unsigned short* dst0 = (matid == 0) ? qb : kb;
#pragma unroll
        for (int it = 0; it < 8; ++it) {
            const int vid = it * 512 + tid;       // 0..4095
            const int head = vid >> 11;
            const int rem = vid & 2047;
            const int tr = rem >> 3, c8 = rem & 7;
            uint4 v = *(const uint4*)&ep[tr * 136 + head * 64 + c8 * 8];
            *(uint4*)&dst0[((size_t)((b * H_ + h0 + head) * T_) + tg0 + tr) * D_
                           + c8 * 8] = v;
        }
    }
    if (matid >= 1) {                    // transposed out: ktb or vtb [B,H,D,T]
        unsigned short* dstT = (matid == 1) ? ktb : vtb;
#pragma unroll
        for (int it = 0; it < 8; ++it) {
            const int vid = it * 512 + tid;
            const int head = vid >> 11;
            const int rem = vid & 2047;
            const int d = rem & 63, t8 = rem >> 6;    // d fast -> conflict-free
            unsigned short vals[8];
#pragma unroll
            for (int i = 0; i < 8; ++i)
                vals[i] = ep[(t8 * 8 + i) * 136 + head * 64 + d];
            *(uint4*)&dstT[((size_t)((b * H_ + h0 + head) * D_) + d) * T_
                           + tg0 + t8 * 8] = *(const uint4*)vals;
        }
    }
}

// ---------------------------------------------------------------------------
// Phase A (MFMA): per-chunk S_local = K^T V (+ z via ones-cols), bf16 out.
// ---------------------------------------------------------------------------
__global__ __launch_bounds__(256) void chunk_sums_mfma(
    const unsigned short* __restrict__ Kt,  // [BH][64][T]
    const unsigned short* __restrict__ Vt,  // [BH][64][T]
    unsigned short* __restrict__ Sl,        // [BH*NC][64*64]
    unsigned short* __restrict__ Zl)        // [BH*NC][64]
{
    const int tid = threadIdx.x, lane = tid & 63, w = tid >> 6;
    const int lo = lane & 15, hi = lane >> 4;
    const int cid = blockIdx.x, bh = cid >> 5, c = cid & 31, t0 = c * CT;
    const unsigned short* kT = Kt + (size_t)bh * 64 * T_ + t0;
    const unsigned short* vT = Vt + (size_t)bh * 64 * T_ + t0;

    const bf16x8 ones8 = {0x3F80, 0x3F80, 0x3F80, 0x3F80,
                          0x3F80, 0x3F80, 0x3F80, 0x3F80};
    f32x4 acc[5] = {};
#pragma unroll
    for (int kt = 0; kt < 4; ++kt) {
        bf16x8 af = *(const bf16x8*)&kT[(size_t)(w * 16 + lo) * T_ + kt * 32 + hi * 8];
        bf16x8 bfr[5];
#pragma unroll
        for (int et = 0; et < 4; ++et)
            bfr[et] = *(const bf16x8*)&vT[(size_t)(et * 16 + lo) * T_ + kt * 32 + hi * 8];
        bfr[4] = ones8;
#pragma unroll
        for (int et = 0; et < 5; ++et)
            acc[et] = __builtin_amdgcn_mfma_f32_16x16x32_bf16(af, bfr[et], acc[et], 0, 0, 0);
    }
    unsigned short* sO = Sl + (size_t)cid * 4096;
    const int d0 = w * 16 + hi * 4;
#pragma unroll
    for (int et = 0; et < 4; ++et) {
        const int e = et * 16 + lo;
        ushort4 pk = make_ushort4(f2bf(acc[et][0]), f2bf(acc[et][1]),
                                  f2bf(acc[et][2]), f2bf(acc[et][3]));
        *(ushort4*)&sO[e * 64 + d0] = pk;
    }
    if (lo == 0) {
        ushort4 pk = make_ushort4(f2bf(acc[4][0]), f2bf(acc[4][1]),
                                  f2bf(acc[4][2]), f2bf(acc[4][3]));
        *(ushort4*)&Zl[(size_t)cid * 64 + d0] = pk;
    }
}

// ---------------------------------------------------------------------------
// Phase B: in-place exclusive prefix over chunks, bf16, f32 accumulation.
// ---------------------------------------------------------------------------
__global__ __launch_bounds__(256) void chunk_scan_bf(
    unsigned short* __restrict__ S, unsigned short* __restrict__ Z)
{
    const int bh = blockIdx.y;
    const int f0 = blockIdx.x * 512 + threadIdx.x * 2;
    float a0 = 0.f, a1 = 0.f;
    unsigned short* base = S + (size_t)bh * NC * 4096 + f0;
    for (int c = 0; c < NC; ++c) {
        uint32_t* p = (uint32_t*)(base + (size_t)c * 4096);
        uint32_t v = *p;
        float c0 = bf2f(v & 0xffffu), c1 = bf2f(v >> 16);
        *p = (uint32_t)f2bf(a0) | ((uint32_t)f2bf(a1) << 16);
        a0 += c0; a1 += c1;
    }
    if (blockIdx.x == 0 && threadIdx.x < 32) {
        float b0 = 0.f, b1 = 0.f;
        unsigned short* zb = Z + (size_t)bh * NC * 64 + threadIdx.x * 2;
        for (int c = 0; c < NC; ++c) {
            uint32_t* p = (uint32_t*)(zb + (size_t)c * 64);
            uint32_t v = *p;
            float c0 = bf2f(v & 0xffffu), c1 = bf2f(v >> 16);
            *p = (uint32_t)f2bf(b0) | ((uint32_t)f2bf(b1) << 16);
            b0 += c0; b1 += c1;
        }
    }
}

// ---------------------------------------------------------------------------
// Phase C (MFMA): P^T = K.Q^T (masked), numext = Q.[Sp|z] + P.[V|1].
// ---------------------------------------------------------------------------
__global__ __launch_bounds__(256) void chunk_attn_mfma(
    const unsigned short* __restrict__ Qb,  // [BH][T][64]
    const unsigned short* __restrict__ Kb,  // [BH][T][64]
    const unsigned short* __restrict__ Vt,  // [BH][64][T]
    const unsigned short* __restrict__ SpT, // [BH*NC][64*64] prefix [e][d]
    const unsigned short* __restrict__ Zp,  // [BH*NC][64] prefix
    unsigned short* __restrict__ att)       // [M][1024]
{
    __shared__ unsigned short lds[128 * 128];

    const int tid = threadIdx.x;
    const int lane = tid & 63;
    const int w = tid >> 6;
    const int lo = lane & 15, hi = lane >> 4;
    const int cid = blockIdx.x;
    const int bh = cid >> 5, c = cid & 31;
    const int t0 = c * CT;

    const unsigned short* qB = Qb + ((size_t)bh * T_ + t0) * 64;
    const unsigned short* kB = Kb + ((size_t)bh * T_ + t0) * 64;
    const unsigned short* vB = Vt + (size_t)bh * 64 * T_ + t0;
    const unsigned short* sB = SpT + (size_t)cid * 4096;
    const unsigned short* zB = Zp + (size_t)cid * 64;

    bf16x8 ka[2][2];
#pragma unroll
    for (int si = 0; si < 2; ++si)
#pragma unroll
        for (int kt = 0; kt < 2; ++kt)
            ka[si][kt] = *(const bf16x8*)&kB[(w * 32 + si * 16 + lo) * 64 + kt * 32 + hi * 8];

    f32x4 pacc[2][8] = {};
#pragma unroll
    for (int ti = 0; ti < 8; ++ti) {
        if (ti >= 2 * w) {
#pragma unroll
            for (int kt = 0; kt < 2; ++kt) {
                bf16x8 qf = *(const bf16x8*)&qB[(ti * 16 + lo) * 64 + kt * 32 + hi * 8];
                pacc[0][ti] = __builtin_amdgcn_mfma_f32_16x16x32_bf16(
                    ka[0][kt], qf, pacc[0][ti], 0, 0, 0);
                if (ti >= 2 * w + 1)
                    pacc[1][ti] = __builtin_amdgcn_mfma_f32_16x16x32_bf16(
                        ka[1][kt], qf, pacc[1][ti], 0, 0, 0);
            }
        }
    }
#pragma unroll
    for (int ti = 0; ti < 8; ++ti) {
        if (ti >= 2 * w) {
            const int t = ti * 16 + lo;
#pragma unroll
            for (int si = 0; si < 2; ++si) {
                const int s0 = w * 32 + si * 16 + hi * 4;
                ushort4 pk;
                unsigned short* pe = (unsigned short*)&pk;
#pragma unroll
                for (int j = 0; j < 4; ++j)
                    pe[j] = (s0 + j <= t) ? f2bf(pacc[si][ti][j]) : (unsigned short)0;
                *(ushort4*)((char*)lds + t * 256 + ((s0 * 2) ^ ((t & 7) << 4))) = pk;
            }
        }
    }
    __syncthreads();

    const bf16x8 ones8 = {0x3F80, 0x3F80, 0x3F80, 0x3F80,
                          0x3F80, 0x3F80, 0x3F80, 0x3F80};
    f32x4 acc[2][5] = {};
#pragma unroll
    for (int kt = 0; kt < 6; ++kt) {
        const int skt = kt - 2;
        if (kt < 2 || skt <= w) {
            bf16x8 bfr[5];
            if (kt < 2) {
#pragma unroll
                for (int et = 0; et < 4; ++et)
                    bfr[et] = *(const bf16x8*)&sB[(et * 16 + lo) * 64 + kt * 32 + hi * 8];
                bfr[4] = *(const bf16x8*)&zB[kt * 32 + hi * 8];
            } else {
#pragma unroll
                for (int et = 0; et < 4; ++et)
                    bfr[et] = *(const bf16x8*)&vB[(size_t)(et * 16 + lo) * T_ + skt * 32 + hi * 8];
                bfr[4] = ones8;
            }
#pragma unroll
            for (int m = 0; m < 2; ++m) {
                const int t = w * 32 + m * 16 + lo;
                bf16x8 af;
                if (kt < 2)
                    af = *(const bf16x8*)&qB[t * 64 + kt * 32 + hi * 8];
                else
                    af = *(const bf16x8*)((char*)lds + t * 256 +
                         (((skt * 32 + hi * 8) * 2) ^ ((t & 7) << 4)));
#pragma unroll
                for (int et = 0; et < 5; ++et)
                    acc[m][et] = __builtin_amdgcn_mfma_f32_16x16x32_bf16(
                        af, bfr[et], acc[m][et], 0, 0, 0);
            }
        }
    }

    __syncthreads();
#pragma unroll
    for (int m = 0; m < 2; ++m) {
#pragma unroll
        for (int j = 0; j < 4; ++j) {
            const int t = w * 32 + m * 16 + hi * 4 + j;
            const float rden = 1.f / (acc[m][4][j] + EPSC);
#pragma unroll
            for (int et = 0; et < 4; ++et) {
                const int e = et * 16 + lo;
                *(unsigned short*)((char*)lds + t * 144 + e * 2) =
                    f2bf(acc[m][et][j] * rden);
            }
        }
    }
    __syncthreads();
    const int b = bh >> 4, h = bh & 15;
#pragma unroll
    for (int r = 0; r < 4; ++r) {
        const int vid = tid + r * 256;
        const int t = vid >> 3, eg = vid & 7;
        uint4 val = *(const uint4*)((const char*)lds + t * 144 + eg * 16);
        *(uint4*)&att[(size_t)(b * T_ + t0 + t) * E_ + h * 64 + eg * 8] = val;
    }
}

// ---------------------------------------------------------------------------
extern "C" void kernel_launch(void* const* d_in, const int* in_sizes, int n_in,
                              void* d_out, int out_size, void* d_ws, size_t ws_size,
                              hipStream_t stream)
{
    const float* x  = (const float*)d_in[0];
    const float* wq = (const float*)d_in[1];
    const float* bq = (const float*)d_in[2];
    const float* wk = (const float*)d_in[3];
    const float* bk = (const float*)d_in[4];
    const float* wv = (const float*)d_in[5];
    const float* bv = (const float*)d_in[6];
    const float* wo = (const float*)d_in[7];
    const float* bo = (const float*)d_in[8];
    float* out = (float*)d_out;

    // workspace layout (MB): qb 0-16 | kb 16-32 | ktb 32-48 | vtb 48-64 |
    //   xb 64-80 (aliased by attb) | Sl 80-88 | Zl 88-88.125 | wT 88.125-96.125
    char* ws = (char*)d_ws;
    unsigned short* qb  = (unsigned short*)(ws);
    unsigned short* kb  = (unsigned short*)(ws + (size_t)16 * 1024 * 1024);
    unsigned short* ktb = (unsigned short*)(ws + (size_t)32 * 1024 * 1024);
    unsigned short* vtb = (unsigned short*)(ws + (size_t)48 * 1024 * 1024);
    unsigned short* xb  = (unsigned short*)(ws + (size_t)64 * 1024 * 1024);
    unsigned short* attb = xb;   // xb dead after QKV GEMM
    unsigned short* Sl  = (unsigned short*)(ws + (size_t)80 * 1024 * 1024);
    unsigned short* Zl  = (unsigned short*)(ws + (size_t)88 * 1024 * 1024);
    unsigned short* wqT = (unsigned short*)(ws + (size_t)88 * 1024 * 1024 + 128 * 1024);
    unsigned short* wkT = wqT + (size_t)KDIM * NDIM;   // contiguous [3072][1024]
    unsigned short* wvT = wkT + (size_t)KDIM * NDIM;
    unsigned short* woT = wvT + (size_t)KDIM * NDIM;

    prep<<<dim3(16, 16, 5), 256, 0, stream>>>(x, xb, wq, wk, wv, wo,
                                              wqT, wkT, wvT, woT);

    gemm_tb<0><<<768, 512, 0, stream>>>(xb, wqT, bq, bk, bv,
                                        qb, kb, ktb, vtb, nullptr);

    chunk_sums_mfma<<<B_ * H_ * NC, 256, 0, stream>>>(ktb, vtb, Sl, Zl);
    chunk_scan_bf<<<dim3(8, B_ * H_), 256, 0, stream>>>(Sl, Zl);
    chunk_attn_mfma<<<B_ * H_ * NC, 256, 0, stream>>>(qb, kb, vtb, Sl, Zl, attb);

    gemm_tb<1><<<256, 512, 0, stream>>>(attb, woT, bo, nullptr, nullptr,
                                        nullptr, nullptr, nullptr, nullptr, out);
}